// Round 5
// baseline (579.294 us; speedup 1.0000x reference)
//
#include <hip/hip_runtime.h>

#define N_NODES 20000
#define N_EDGES 640000
#define N_MT (N_EDGES/16)   // 40000 microtiles of 16 edges

typedef short short8 __attribute__((ext_vector_type(8)));
typedef float f32x4 __attribute__((ext_vector_type(4)));

// RNE float -> bf16 bits
__device__ __forceinline__ unsigned short f2bf(float x){
  unsigned int u = __builtin_bit_cast(unsigned int, x);
  u += 0x7fffu + ((u >> 16) & 1u);
  return (unsigned short)(u >> 16);
}

// wave-synchronous LDS phase boundary
__device__ __forceinline__ void wave_lds_fence(){
  __asm__ volatile("s_waitcnt lgkmcnt(0)" ::: "memory");
}

#define HIST_BLOCKS ((N_EDGES+255)/256)    // 2500
#define Y_BLOCKS    ((N_NODES*80+255)/256) // 6250

// ---------------- fused: edge-dst histogram + y = per-irrep linear (l1) ----
__global__ void k_pre(const int* __restrict__ ei, int* __restrict__ counts,
                      const float* __restrict__ ni, const float* __restrict__ na,
                      const float* __restrict__ Wl10, const float* __restrict__ Wl11,
                      float* __restrict__ y){
  if (blockIdx.x < HIST_BLOCKS){
    int e = blockIdx.x*256 + threadIdx.x;
    if (e < N_EDGES) atomicAdd(&counts[ei[N_EDGES + e]], 1);
    return;
  }
  int gid = (blockIdx.x - HIST_BLOCKS)*256 + threadIdx.x;
  if (gid >= N_NODES*80) return;
  int n = gid / 80, k = gid - n*80;
  const float* row = ni + (size_t)n*80;
  float a = na[n];
  float acc = 0.f;
  if (k < 32){
    #pragma unroll
    for (int u=0; u<32; ++u) acc += row[u]*Wl10[u*32+k];
    y[gid] = acc * a * 0.17677669529663687f;  // 1/sqrt(32)
  } else {
    int kk = k-32, v = kk/3, i = kk - v*3;
    #pragma unroll
    for (int u=0; u<16; ++u) acc += row[32+u*3+i]*Wl11[u*16+v];
    y[gid] = acc * a * 0.25f;                  // 1/sqrt(16)
  }
}

__global__ void k_alloc(const int* __restrict__ counts, int* __restrict__ ctr,
                        int* __restrict__ cursor){
  int n = blockIdx.x*256 + threadIdx.x;
  if (n < N_NODES) cursor[n] = atomicAdd(ctr, counts[n]);
}

// Pack each edge's full record into one 64B line at its sorted position:
// f[16] = {src, dst, ea0, ea1, ea2, ea3, es0..es9}
__global__ void k_fill(const int* __restrict__ ei, const float* __restrict__ ea,
                       const float* __restrict__ es, int* __restrict__ cursor,
                       float4* __restrict__ meta){
  int e = blockIdx.x*256 + threadIdx.x;
  if (e >= N_EDGES) return;
  int s = ei[e], d = ei[N_EDGES + e];
  int pos = atomicAdd(&cursor[d], 1);
  const float* eap = ea + (size_t)e*4;
  const float* esp = es + (size_t)e*10;
  float4 v0, v1, v2, v3;
  v0.x = __int_as_float(s); v0.y = __int_as_float(d); v0.z = eap[0]; v0.w = eap[1];
  v1.x = eap[2]; v1.y = eap[3]; v1.z = esp[0]; v1.w = esp[1];
  v2.x = esp[2]; v2.y = esp[3]; v2.z = esp[4]; v2.w = esp[5];
  v3.x = esp[6]; v3.y = esp[7]; v3.z = esp[8]; v3.w = esp[9];
  float4* mp = meta + (size_t)pos*4;
  mp[0] = v0; mp[1] = v1; mp[2] = v2; mp[3] = v3;
}

// ---------------- fused edge MLP + messages + segment-sum ----------------
// Per-wave autonomous + software-pipelined: meta for tile m+1 prefetched
// during layer1; y rows for m+1 prefetched during MFMA/messages.
// NOTE: tile m spans float4 indices [64m, 64m+64) — 4 float4s per edge.
__global__ __launch_bounds__(256, 3) void k_edge(
    const float4* __restrict__ meta,
    const float* __restrict__ Wfc0, const float* __restrict__ Wfc1,
    const float* __restrict__ y, float* __restrict__ agg){
  __shared__ float s_wfc0[640];          // [k=10][n=64] f32, block-shared
  __shared__ float s_w [4][16*98];       // per-wave: [e=16][o=96(+2)]
  __shared__ float s_y [4][16*80];       // per-wave: gathered y rows
  __shared__ float s_m [4][16*16];       // per-wave: packed meta rows

  const int t = threadIdx.x;
  const int w = t >> 6, l = t & 63;
  const int r = l & 15, part = l >> 4;

  for (int i = t; i < 640; i += 256) s_wfc0[i] = Wfc0[i];

  // B-fragments of Wfc1 (bf16) in registers: lane holds B[k=part*8+j][n=nt*16+r]
  short8 b0[6], b1[6];
  #pragma unroll
  for (int nt=0; nt<6; ++nt){
    #pragma unroll
    for (int j=0; j<8; ++j){
      b0[nt][j] = (short)f2bf(Wfc1[(     part*8+j)*96 + nt*16 + r]);
      b1[nt][j] = (short)f2bf(Wfc1[(32 + part*8+j)*96 + nt*16 + r]);
    }
  }
  __syncthreads();   // only block barrier: s_wfc0 ready

  // per-lane message-channel constants (3 channel passes, c = p*64 + l)
  int o_c[3], yo[3], eai[3];
  #pragma unroll
  for (int p=0; p<3; ++p){
    int c = p*64 + l;
    if (c < 32)      { o_c[p]=c;    yo[p]=c;        eai[p]=0; }
    else if (c < 48) { int u=c-32;  o_c[p]=80+u;    yo[p]=32+3*u; eai[p]=0; }
    else if (c < 144){ int idx=c-48;  int u=idx/3, fi=idx-u*3; o_c[p]=32+u; yo[p]=u;        eai[p]=1+fi; }
    else             { int idx=c-144; int u=idx/3, i =idx-u*3; o_c[p]=64+u; yo[p]=32+3*u+i; eai[p]=0; }
  }
  const bool dot0 = (l >= 32) && (l < 48);

  float* sw = s_w[w];
  float* sy = s_y[w];
  float* sm = s_m[w];

  const int gw = blockIdx.x*4 + w;
  const int nw = gridDim.x*4;
  const int m0 = (int)(((long long)gw     * N_MT) / nw);
  const int m1 = (int)(((long long)(gw+1) * N_MT) / nw);
  if (m0 >= m1) return;

  // ---- prologue: load tile m0 meta + y rows into registers
  float4 mreg = meta[(size_t)m0*64 + l];
  float4 yreg[5];
  {
    int srcv = __float_as_int(__shfl(mreg.x, 4*r));
    const float4* yp = (const float4*)(y + (size_t)srcv*80 + part*20);
    #pragma unroll
    for (int q=0; q<5; ++q) yreg[q] = yp[q];
  }

  float acc0 = 0.f, acc1 = 0.f, acc2 = 0.f;
  int dcur = -1;

  for (int m = m0; m < m1; ++m){
    // ---- stage current tile (registers -> LDS), start meta prefetch
    *(float4*)(sm + l*4) = mreg;
    {
      float4* syp = (float4*)(sy + r*80 + part*20);
      #pragma unroll
      for (int q=0; q<5; ++q) syp[q] = yreg[q];
    }
    const float4 mcur = mreg;
    const bool have_next = (m+1 < m1);
    if (have_next) mreg = meta[(size_t)(m+1)*64 + l];
    wave_lds_fence();

    // ---- layer1: h[r][part*8+j], es via shfl from mcur (no LDS conflicts)
    float esv[10];
    esv[0]=__shfl(mcur.z, 4*r+1); esv[1]=__shfl(mcur.w, 4*r+1);
    esv[2]=__shfl(mcur.x, 4*r+2); esv[3]=__shfl(mcur.y, 4*r+2);
    esv[4]=__shfl(mcur.z, 4*r+2); esv[5]=__shfl(mcur.w, 4*r+2);
    esv[6]=__shfl(mcur.x, 4*r+3); esv[7]=__shfl(mcur.y, 4*r+3);
    esv[8]=__shfl(mcur.z, 4*r+3); esv[9]=__shfl(mcur.w, 4*r+3);
    float hv0[8], hv1[8];
    #pragma unroll
    for (int j=0; j<8; ++j){ hv0[j]=0.f; hv1[j]=0.f; }
    #pragma unroll
    for (int k=0; k<10; ++k){
      float ev = esv[k];
      const float* wr = s_wfc0 + k*64 + part*8;
      #pragma unroll
      for (int j=0; j<8; ++j){ hv0[j] += ev*wr[j]; hv1[j] += ev*wr[32+j]; }
    }
    short8 a0, a1;
    #pragma unroll
    for (int j=0; j<8; ++j){
      float x0 = hv0[j]*0.31622776601683794f;   // /sqrt(10)
      float x1 = hv1[j]*0.31622776601683794f;
      a0[j] = (short)f2bf(x0/(1.f+__expf(-x0)));
      a1[j] = (short)f2bf(x1/(1.f+__expf(-x1)));
    }

    // ---- y prefetch for next tile (hidden under MFMA + message loop)
    if (have_next){
      int srcv = __float_as_int(__shfl(mreg.x, 4*r));
      const float4* yp = (const float4*)(y + (size_t)srcv*80 + part*20);
      #pragma unroll
      for (int q=0; q<5; ++q) yreg[q] = yp[q];
    }

    // ---- layer2 MFMA: w[e=part*4+rr][o=nt*16+r]
    #pragma unroll
    for (int nt=0; nt<6; ++nt){
      f32x4 acc = {0.f,0.f,0.f,0.f};
      acc = __builtin_amdgcn_mfma_f32_16x16x32_bf16(a0, b0[nt], acc, 0,0,0);
      acc = __builtin_amdgcn_mfma_f32_16x16x32_bf16(a1, b1[nt], acc, 0,0,0);
      #pragma unroll
      for (int rr=0; rr<4; ++rr)
        sw[(part*4+rr)*98 + nt*16 + r] = acc[rr]*0.125f;   // /sqrt(64)
    }
    wave_lds_fence();

    // ---- messages + carried segment-sum (3 channels per lane)
    for (int e=0; e<16; ++e){
      const float* sme = sm + e*16;
      int de = __float_as_int(sme[1]);
      if (de != dcur){
        if (dcur >= 0){
          unsafeAtomicAdd(&agg[(size_t)dcur*192 +       l], acc0);
          unsafeAtomicAdd(&agg[(size_t)dcur*192 +  64 + l], acc1);
          unsafeAtomicAdd(&agg[(size_t)dcur*192 + 128 + l], acc2);
        }
        acc0 = acc1 = acc2 = 0.f;
        dcur = de;
      }
      const float* swe = sw + e*98;
      const float* sye = sy + e*80;
      float m0v;
      if (dot0){
        m0v = swe[o_c[0]] * (sye[yo[0]]*sme[3] + sye[yo[0]+1]*sme[4] + sye[yo[0]+2]*sme[5])
              * 0.5773502691896258f;   // /sqrt(3)
      } else {
        m0v = swe[o_c[0]] * sye[yo[0]] * sme[2 + eai[0]];
      }
      acc0 += m0v;
      acc1 += swe[o_c[1]] * sye[yo[1]] * sme[2 + eai[1]];
      acc2 += swe[o_c[2]] * sye[yo[2]] * sme[2 + eai[2]];
    }
    wave_lds_fence();
  }
  if (dcur >= 0){
    unsafeAtomicAdd(&agg[(size_t)dcur*192 +       l], acc0);
    unsafeAtomicAdd(&agg[(size_t)dcur*192 +  64 + l], acc1);
    unsafeAtomicAdd(&agg[(size_t)dcur*192 + 128 + l], acc2);
  }
}

// ---------------- finish: z = agg @ W_l2, out = c_s*s + c_x*z ----------------
__global__ void k_finish(const float* __restrict__ ni, const float* __restrict__ na,
    const float* __restrict__ Wsc0, const float* __restrict__ Wsc1,
    const float* __restrict__ Wl20, const float* __restrict__ Wl21,
    const float* __restrict__ agg, float* __restrict__ out){
  int gid = blockIdx.x*256 + threadIdx.x;
  if (gid >= N_NODES*80) return;
  int n = gid / 80, k = gid - n*80;
  const float* row = ni + (size_t)n*80;
  const float* ag  = agg + (size_t)n*192;
  float a = na[n];
  const float c_s = 0.3826834323650898f;   // sin(pi/8)
  const float c_x = 0.9238795325112867f;   // cos(pi/8)
  const float zscale = 0.17677669529663687f * 0.14433756729740643f; // 1/sqrt(32)/sqrt(48)
  float s = 0.f, z = 0.f;
  if (k < 32){
    #pragma unroll
    for (int u=0; u<32; ++u) s += row[u]*Wsc0[u*32+k];
    s *= a * 0.17677669529663687f;
    #pragma unroll
    for (int u=0; u<48; ++u) z += ag[u]*Wl20[u*32+k];
  } else {
    int kk=k-32, v=kk/3, i=kk-v*3;
    #pragma unroll
    for (int u=0; u<16; ++u) s += row[32+u*3+i]*Wsc1[u*16+v];
    s *= a * 0.25f;
    #pragma unroll
    for (int u=0; u<48; ++u) z += ag[48+u*3+i]*Wl21[u*16+v];
  }
  out[gid] = c_s*s + c_x*z*zscale;
}

extern "C" void kernel_launch(void* const* d_in, const int* in_sizes, int n_in,
                              void* d_out, int out_size, void* d_ws, size_t ws_size,
                              hipStream_t stream){
  const float* node_input   = (const float*)d_in[0];
  const float* node_attr    = (const float*)d_in[1];
  const float* edge_attr    = (const float*)d_in[2];
  const float* edge_scalars = (const float*)d_in[3];
  const float* W_sc0 = (const float*)d_in[4];
  const float* W_sc1 = (const float*)d_in[5];
  const float* W_l1_0 = (const float*)d_in[6];
  const float* W_l1_1 = (const float*)d_in[7];
  const float* W_fc0 = (const float*)d_in[8];
  const float* W_fc1 = (const float*)d_in[9];
  const float* W_l2_0 = (const float*)d_in[10];
  const float* W_l2_1 = (const float*)d_in[11];
  const int* edge_index = (const int*)d_in[12];
  float* out = (float*)d_out;

  char* ws = (char*)d_ws;
  float*  y    = (float*)ws;                          //  6,400,000 B
  float*  agg  = (float*)(ws + 6400000);              // 15,360,000 B
  float4* meta = (float4*)(ws + 21760000);            // 40,960,000 B (16B-aligned)
  int* counts  = (int*)(ws + 62720000);               // 20000 ints
  int* ctr     = counts + 20000;                      // 1 int (+7 pad)
  int* cursor  = counts + 20008;                      // 20000 ints

  hipMemsetAsync(agg, 0, (size_t)N_NODES*192*sizeof(float), stream);
  hipMemsetAsync(counts, 0, (size_t)20008*sizeof(int), stream);  // counts + ctr

  k_pre  <<<HIST_BLOCKS + Y_BLOCKS, 256, 0, stream>>>(edge_index, counts,
                                                      node_input, node_attr, W_l1_0, W_l1_1, y);
  k_alloc<<<(N_NODES+255)/256, 256, 0, stream>>>(counts, ctr, cursor);
  k_fill <<<(N_EDGES+255)/256, 256, 0, stream>>>(edge_index, edge_attr, edge_scalars,
                                                 cursor, meta);
  k_edge <<<768, 256, 0, stream>>>(meta, W_fc0, W_fc1, y, agg);
  k_finish<<<(N_NODES*80+255)/256, 256, 0, stream>>>(node_input, node_attr, W_sc0, W_sc1,
                                                     W_l2_0, W_l2_1, agg, out);
}

// Round 6
// 401.287 us; speedup vs baseline: 1.4436x; 1.4436x over previous
//
#include <hip/hip_runtime.h>

#define N_NODES 20000
#define N_EDGES 640000
#define N_MT (N_EDGES/16)   // 40000 microtiles of 16 edges

typedef short short8 __attribute__((ext_vector_type(8)));
typedef float f32x4 __attribute__((ext_vector_type(4)));

// RNE float -> bf16 bits
__device__ __forceinline__ unsigned short f2bf(float x){
  unsigned int u = __builtin_bit_cast(unsigned int, x);
  u += 0x7fffu + ((u >> 16) & 1u);
  return (unsigned short)(u >> 16);
}

// wave-synchronous LDS phase boundary
__device__ __forceinline__ void wave_lds_fence(){
  __asm__ volatile("s_waitcnt lgkmcnt(0)" ::: "memory");
}

#define HIST_BLOCKS ((N_EDGES+255)/256)    // 2500
#define Y_BLOCKS    ((N_NODES*80+255)/256) // 6250

// ---------------- fused: edge-dst histogram + y = per-irrep linear (l1) ----
__global__ void k_pre(const int* __restrict__ ei, int* __restrict__ counts,
                      const float* __restrict__ ni, const float* __restrict__ na,
                      const float* __restrict__ Wl10, const float* __restrict__ Wl11,
                      float* __restrict__ y){
  if (blockIdx.x < HIST_BLOCKS){
    int e = blockIdx.x*256 + threadIdx.x;
    if (e < N_EDGES) atomicAdd(&counts[ei[N_EDGES + e]], 1);
    return;
  }
  int gid = (blockIdx.x - HIST_BLOCKS)*256 + threadIdx.x;
  if (gid >= N_NODES*80) return;
  int n = gid / 80, k = gid - n*80;
  const float* row = ni + (size_t)n*80;
  float a = na[n];
  float acc = 0.f;
  if (k < 32){
    #pragma unroll
    for (int u=0; u<32; ++u) acc += row[u]*Wl10[u*32+k];
    y[gid] = acc * a * 0.17677669529663687f;  // 1/sqrt(32)
  } else {
    int kk = k-32, v = kk/3, i = kk - v*3;
    #pragma unroll
    for (int u=0; u<16; ++u) acc += row[32+u*3+i]*Wl11[u*16+v];
    y[gid] = acc * a * 0.25f;                  // 1/sqrt(16)
  }
}

__global__ void k_alloc(const int* __restrict__ counts, int* __restrict__ ctr,
                        int* __restrict__ cursor){
  int n = blockIdx.x*256 + threadIdx.x;
  if (n < N_NODES) cursor[n] = atomicAdd(ctr, counts[n]);
}

// Pack each edge's ea+es into one 64B record at its sorted position:
// f[16] = {ea0..ea3, es0..es9, pad, pad}; src/dst in separate sorted arrays.
__global__ void k_fill(const int* __restrict__ ei, const float* __restrict__ ea,
                       const float* __restrict__ es, int* __restrict__ cursor,
                       float4* __restrict__ meta, int* __restrict__ srcs,
                       int* __restrict__ dsts){
  int e = blockIdx.x*256 + threadIdx.x;
  if (e >= N_EDGES) return;
  int s = ei[e], d = ei[N_EDGES + e];
  int pos = atomicAdd(&cursor[d], 1);
  const float* eap = ea + (size_t)e*4;
  const float* esp = es + (size_t)e*10;
  float4 v0, v1, v2, v3;
  v0.x = eap[0]; v0.y = eap[1]; v0.z = eap[2]; v0.w = eap[3];
  v1.x = esp[0]; v1.y = esp[1]; v1.z = esp[2]; v1.w = esp[3];
  v2.x = esp[4]; v2.y = esp[5]; v2.z = esp[6]; v2.w = esp[7];
  v3.x = esp[8]; v3.y = esp[9]; v3.z = 0.f;    v3.w = 0.f;
  float4* mp = meta + (size_t)pos*4;
  mp[0] = v0; mp[1] = v1; mp[2] = v2; mp[3] = v3;
  srcs[pos] = s;
  dsts[pos] = d;
}

// ---------------- fused edge MLP + messages + segment-sum ----------------
// Per-wave autonomous (round-3 flow): y rows go global->reg->LDS immediately
// (short live ranges, no spills). Only next-tile meta/src/dst (7 VGPRs) is
// prefetched across the compute phases.
// Tile m spans meta float4 indices [64m, 64m+64) — 4 float4s per edge.
__global__ __launch_bounds__(256, 3) void k_edge(
    const float4* __restrict__ meta, const int* __restrict__ srcs,
    const int* __restrict__ dsts,
    const float* __restrict__ Wfc0, const float* __restrict__ Wfc1,
    const float* __restrict__ y, float* __restrict__ agg){
  __shared__ float s_wfc0[640];          // [k=10][n=64] f32, block-shared
  __shared__ float s_w [4][16*98];       // per-wave: [e=16][o=96(+2)]
  __shared__ float s_y [4][16*84];       // per-wave: y rows, stride 84 (21x16B)
  __shared__ float s_m [4][16*20];       // per-wave: ea[0..3], es[4..13]

  const int t = threadIdx.x;
  const int w = t >> 6, l = t & 63;
  const int r = l & 15, part = l >> 4;

  for (int i = t; i < 640; i += 256) s_wfc0[i] = Wfc0[i];

  // B-fragments of Wfc1 (bf16) in registers: lane holds B[k=part*8+j][n=nt*16+r]
  short8 b0[6], b1[6];
  #pragma unroll
  for (int nt=0; nt<6; ++nt){
    #pragma unroll
    for (int j=0; j<8; ++j){
      b0[nt][j] = (short)f2bf(Wfc1[(     part*8+j)*96 + nt*16 + r]);
      b1[nt][j] = (short)f2bf(Wfc1[(32 + part*8+j)*96 + nt*16 + r]);
    }
  }
  __syncthreads();   // only block barrier: s_wfc0 ready

  // per-lane message-channel constants (3 channel passes, c = p*64 + l)
  int o_c[3], yo[3], eai[3];
  #pragma unroll
  for (int p=0; p<3; ++p){
    int c = p*64 + l;
    if (c < 32)      { o_c[p]=c;    yo[p]=c;        eai[p]=0; }
    else if (c < 48) { int u=c-32;  o_c[p]=80+u;    yo[p]=32+3*u; eai[p]=0; }
    else if (c < 144){ int idx=c-48;  int u=idx/3, fi=idx-u*3; o_c[p]=32+u; yo[p]=u;        eai[p]=1+fi; }
    else             { int idx=c-144; int u=idx/3, i =idx-u*3; o_c[p]=64+u; yo[p]=32+3*u+i; eai[p]=0; }
  }
  const bool dot0 = (l >= 32) && (l < 48);

  float* sw = s_w[w];
  float* sy = s_y[w];
  float* sm = s_m[w];

  const int gw = blockIdx.x*4 + w;
  const int nw = gridDim.x*4;
  const int m0 = (int)(((long long)gw     * N_MT) / nw);
  const int m1 = (int)(((long long)(gw+1) * N_MT) / nw);
  if (m0 >= m1) return;

  // ---- prologue: tile m0 meta/src/dst
  float4 mreg = meta[(size_t)m0*64 + l];
  int isrc = srcs[m0*16 + r];
  int idst = dsts[m0*16 + r];

  float acc0 = 0.f, acc1 = 0.f, acc2 = 0.f;
  int dcur = -1;

  for (int m = m0; m < m1; ++m){
    // ---- current-tile y gather (global->reg->LDS, short live range)
    float4 yv0, yv1, yv2, yv3, yv4;
    {
      const float4* yp = (const float4*)(y + (size_t)isrc*80 + part*20);
      yv0 = yp[0]; yv1 = yp[1]; yv2 = yp[2]; yv3 = yp[3]; yv4 = yp[4];
    }
    // ---- next-tile prefetch (small: 7 VGPRs live across compute)
    float4 mnext = mreg; int isrc2 = isrc, idst2 = idst;
    if (m+1 < m1){
      mnext = meta[(size_t)(m+1)*64 + l];
      isrc2 = srcs[(m+1)*16 + r];
      idst2 = dsts[(m+1)*16 + r];
    }
    // ---- stage LDS
    *(float4*)(sm + (l>>2)*20 + (l&3)*4) = mreg;   // lane l = quarter (l&3) of edge (l>>2)
    {
      float* syp = sy + r*84 + part*20;
      *(float4*)(syp     ) = yv0;
      *(float4*)(syp +  4) = yv1;
      *(float4*)(syp +  8) = yv2;
      *(float4*)(syp + 12) = yv3;
      *(float4*)(syp + 16) = yv4;
    }
    wave_lds_fence();

    // ---- layer1: h[r][part*8+j] from s_m es
    const float* esr = sm + r*20 + 4;
    float hv0[8], hv1[8];
    #pragma unroll
    for (int j=0; j<8; ++j){ hv0[j]=0.f; hv1[j]=0.f; }
    #pragma unroll
    for (int k=0; k<10; ++k){
      float ev = esr[k];
      const float* wr = s_wfc0 + k*64 + part*8;
      #pragma unroll
      for (int j=0; j<8; ++j){ hv0[j] += ev*wr[j]; hv1[j] += ev*wr[32+j]; }
    }
    short8 a0, a1;
    #pragma unroll
    for (int j=0; j<8; ++j){
      float x0 = hv0[j]*0.31622776601683794f;   // /sqrt(10)
      float x1 = hv1[j]*0.31622776601683794f;
      a0[j] = (short)f2bf(x0/(1.f+__expf(-x0)));
      a1[j] = (short)f2bf(x1/(1.f+__expf(-x1)));
    }

    // ---- layer2 MFMA: w[e=part*4+rr][o=nt*16+r]
    #pragma unroll
    for (int nt=0; nt<6; ++nt){
      f32x4 acc = {0.f,0.f,0.f,0.f};
      acc = __builtin_amdgcn_mfma_f32_16x16x32_bf16(a0, b0[nt], acc, 0,0,0);
      acc = __builtin_amdgcn_mfma_f32_16x16x32_bf16(a1, b1[nt], acc, 0,0,0);
      #pragma unroll
      for (int rr=0; rr<4; ++rr)
        sw[(part*4+rr)*98 + nt*16 + r] = acc[rr]*0.125f;   // /sqrt(64)
    }
    wave_lds_fence();

    // ---- messages + carried segment-sum (3 channels per lane)
    for (int e=0; e<16; ++e){
      int de = __shfl(idst, e);
      if (de != dcur){
        if (dcur >= 0){
          unsafeAtomicAdd(&agg[(size_t)dcur*192 +       l], acc0);
          unsafeAtomicAdd(&agg[(size_t)dcur*192 +  64 + l], acc1);
          unsafeAtomicAdd(&agg[(size_t)dcur*192 + 128 + l], acc2);
        }
        acc0 = acc1 = acc2 = 0.f;
        dcur = de;
      }
      const float* sme = sm + e*20;
      const float* swe = sw + e*98;
      const float* sye = sy + e*84;
      float m0v;
      if (dot0){
        m0v = swe[o_c[0]] * (sye[yo[0]]*sme[1] + sye[yo[0]+1]*sme[2] + sye[yo[0]+2]*sme[3])
              * 0.5773502691896258f;   // /sqrt(3)
      } else {
        m0v = swe[o_c[0]] * sye[yo[0]] * sme[eai[0]];
      }
      acc0 += m0v;
      acc1 += swe[o_c[1]] * sye[yo[1]] * sme[eai[1]];
      acc2 += swe[o_c[2]] * sye[yo[2]] * sme[eai[2]];
    }
    wave_lds_fence();

    mreg = mnext; isrc = isrc2; idst = idst2;
  }
  if (dcur >= 0){
    unsafeAtomicAdd(&agg[(size_t)dcur*192 +       l], acc0);
    unsafeAtomicAdd(&agg[(size_t)dcur*192 +  64 + l], acc1);
    unsafeAtomicAdd(&agg[(size_t)dcur*192 + 128 + l], acc2);
  }
}

// ---------------- finish: z = agg @ W_l2, out = c_s*s + c_x*z ----------------
__global__ void k_finish(const float* __restrict__ ni, const float* __restrict__ na,
    const float* __restrict__ Wsc0, const float* __restrict__ Wsc1,
    const float* __restrict__ Wl20, const float* __restrict__ Wl21,
    const float* __restrict__ agg, float* __restrict__ out){
  int gid = blockIdx.x*256 + threadIdx.x;
  if (gid >= N_NODES*80) return;
  int n = gid / 80, k = gid - n*80;
  const float* row = ni + (size_t)n*80;
  const float* ag  = agg + (size_t)n*192;
  float a = na[n];
  const float c_s = 0.3826834323650898f;   // sin(pi/8)
  const float c_x = 0.9238795325112867f;   // cos(pi/8)
  const float zscale = 0.17677669529663687f * 0.14433756729740643f; // 1/sqrt(32)/sqrt(48)
  float s = 0.f, z = 0.f;
  if (k < 32){
    #pragma unroll
    for (int u=0; u<32; ++u) s += row[u]*Wsc0[u*32+k];
    s *= a * 0.17677669529663687f;
    #pragma unroll
    for (int u=0; u<48; ++u) z += ag[u]*Wl20[u*32+k];
  } else {
    int kk=k-32, v=kk/3, i=kk-v*3;
    #pragma unroll
    for (int u=0; u<16; ++u) s += row[32+u*3+i]*Wsc1[u*16+v];
    s *= a * 0.25f;
    #pragma unroll
    for (int u=0; u<48; ++u) z += ag[48+u*3+i]*Wl21[u*16+v];
  }
  out[gid] = c_s*s + c_x*z*zscale;
}

extern "C" void kernel_launch(void* const* d_in, const int* in_sizes, int n_in,
                              void* d_out, int out_size, void* d_ws, size_t ws_size,
                              hipStream_t stream){
  const float* node_input   = (const float*)d_in[0];
  const float* node_attr    = (const float*)d_in[1];
  const float* edge_attr    = (const float*)d_in[2];
  const float* edge_scalars = (const float*)d_in[3];
  const float* W_sc0 = (const float*)d_in[4];
  const float* W_sc1 = (const float*)d_in[5];
  const float* W_l1_0 = (const float*)d_in[6];
  const float* W_l1_1 = (const float*)d_in[7];
  const float* W_fc0 = (const float*)d_in[8];
  const float* W_fc1 = (const float*)d_in[9];
  const float* W_l2_0 = (const float*)d_in[10];
  const float* W_l2_1 = (const float*)d_in[11];
  const int* edge_index = (const int*)d_in[12];
  float* out = (float*)d_out;

  char* ws = (char*)d_ws;
  float*  y    = (float*)ws;                          //  6,400,000 B
  float*  agg  = (float*)(ws + 6400000);              // 15,360,000 B
  float4* meta = (float4*)(ws + 21760000);            // 40,960,000 B (16B-aligned)
  int* counts  = (int*)(ws + 62720000);               // 20000 ints
  int* ctr     = counts + 20000;                      // 1 int (+7 pad)
  int* cursor  = counts + 20008;                      // 20000 ints
  int* srcs    = cursor + 20000;                      // 640000 ints
  int* dsts    = srcs + N_EDGES;                      // 640000 ints

  hipMemsetAsync(agg, 0, (size_t)N_NODES*192*sizeof(float), stream);
  hipMemsetAsync(counts, 0, (size_t)20008*sizeof(int), stream);  // counts + ctr

  k_pre  <<<HIST_BLOCKS + Y_BLOCKS, 256, 0, stream>>>(edge_index, counts,
                                                      node_input, node_attr, W_l1_0, W_l1_1, y);
  k_alloc<<<(N_NODES+255)/256, 256, 0, stream>>>(counts, ctr, cursor);
  k_fill <<<(N_EDGES+255)/256, 256, 0, stream>>>(edge_index, edge_attr, edge_scalars,
                                                 cursor, meta, srcs, dsts);
  k_edge <<<768, 256, 0, stream>>>(meta, srcs, dsts, W_fc0, W_fc1, y, agg);
  k_finish<<<(N_NODES*80+255)/256, 256, 0, stream>>>(node_input, node_attr, W_sc0, W_sc1,
                                                     W_l2_0, W_l2_1, agg, out);
}

// Round 7
// 396.997 us; speedup vs baseline: 1.4592x; 1.0108x over previous
//
#include <hip/hip_runtime.h>

#define N_NODES 20000
#define N_EDGES 640000
#define N_MT (N_EDGES/16)   // 40000 microtiles of 16 edges

typedef short short8 __attribute__((ext_vector_type(8)));
typedef float f32x4 __attribute__((ext_vector_type(4)));

// RNE float -> bf16 bits
__device__ __forceinline__ unsigned short f2bf(float x){
  unsigned int u = __builtin_bit_cast(unsigned int, x);
  u += 0x7fffu + ((u >> 16) & 1u);
  return (unsigned short)(u >> 16);
}

// wave-synchronous LDS phase boundary
__device__ __forceinline__ void wave_lds_fence(){
  __asm__ volatile("s_waitcnt lgkmcnt(0)" ::: "memory");
}

#define HIST_BLOCKS ((N_EDGES+255)/256)    // 2500
#define YN_BLOCKS   (N_NODES/16)           // 1250 (16 nodes per block)

// ---------------- fused: edge-dst histogram + y = per-irrep linear (l1) ----
// y-part: LDS-staged, 16 nodes/block, 5 outputs/thread.
__global__ void k_pre(const int* __restrict__ ei, int* __restrict__ counts,
                      const float* __restrict__ ni, const float* __restrict__ na,
                      const float* __restrict__ Wl10, const float* __restrict__ Wl11,
                      float* __restrict__ y){
  if (blockIdx.x < HIST_BLOCKS){
    int e = blockIdx.x*256 + threadIdx.x;
    if (e < N_EDGES) atomicAdd(&counts[ei[N_EDGES + e]], 1);
    return;
  }
  __shared__ float sW0[1024];     // Wl10 [32][32]
  __shared__ float sW1[256];      // Wl11 [16][16]
  __shared__ float sni[16*84];    // 16 node rows, stride 84
  __shared__ float sna[16];
  const int t = threadIdx.x;
  const int nb = (blockIdx.x - HIST_BLOCKS)*16;
  for (int i=t; i<1024; i+=256) sW0[i] = Wl10[i];
  if (t < 256) sW1[t] = Wl11[t];
  for (int i=t; i<320; i+=256){
    int n = i/20, q = i - n*20;
    *(float4*)&sni[n*84 + q*4] = *(const float4*)(ni + (size_t)(nb+n)*80 + q*4);
  }
  if (t < 16) sna[t] = na[nb + t];
  __syncthreads();
  for (int i=t; i<1280; i+=256){
    int n = i/80, k = i - n*80;
    const float* row = sni + n*84;
    float a = sna[n];
    float acc = 0.f;
    if (k < 32){
      #pragma unroll
      for (int u=0; u<32; ++u) acc += row[u]*sW0[u*32+k];
      y[(size_t)nb*80 + i] = acc * a * 0.17677669529663687f;  // 1/sqrt(32)
    } else {
      int kk = k-32, v = kk/3, ii = kk - v*3;
      #pragma unroll
      for (int u=0; u<16; ++u) acc += row[32+u*3+ii]*sW1[u*16+v];
      y[(size_t)nb*80 + i] = acc * a * 0.25f;                  // 1/sqrt(16)
    }
  }
}

__global__ void k_alloc(const int* __restrict__ counts, int* __restrict__ ctr,
                        int* __restrict__ cursor){
  int n = blockIdx.x*256 + threadIdx.x;
  if (n < N_NODES) cursor[n] = atomicAdd(ctr, counts[n]);
}

// Pack each edge's ea+es into one 64B record at its sorted position:
// f[16] = {ea0..ea3, es0..es9, pad, pad}; src/dst in separate sorted arrays.
__global__ void k_fill(const int* __restrict__ ei, const float* __restrict__ ea,
                       const float* __restrict__ es, int* __restrict__ cursor,
                       float4* __restrict__ meta, int* __restrict__ srcs,
                       int* __restrict__ dsts){
  int e = blockIdx.x*256 + threadIdx.x;
  if (e >= N_EDGES) return;
  int s = ei[e], d = ei[N_EDGES + e];
  int pos = atomicAdd(&cursor[d], 1);
  const float* eap = ea + (size_t)e*4;
  const float* esp = es + (size_t)e*10;
  float4 v0, v1, v2, v3;
  v0.x = eap[0]; v0.y = eap[1]; v0.z = eap[2]; v0.w = eap[3];
  v1.x = esp[0]; v1.y = esp[1]; v1.z = esp[2]; v1.w = esp[3];
  v2.x = esp[4]; v2.y = esp[5]; v2.z = esp[6]; v2.w = esp[7];
  v3.x = esp[8]; v3.y = esp[9]; v3.z = 0.f;    v3.w = 0.f;
  float4* mp = meta + (size_t)pos*4;
  mp[0] = v0; mp[1] = v1; mp[2] = v2; mp[3] = v3;
  srcs[pos] = s;
  dsts[pos] = d;
}

// ---------------- fused edge MLP + messages + segment-sum ----------------
// Per-wave autonomous, software-pipelined. Next-tile y prefetch is issued
// AFTER the MFMA phase (live only across message loop) and is UNCONDITIONAL
// with a clamped index — the round-5 spill came from conditional vector
// defs at the loop merge, not register pressure.
__global__ __launch_bounds__(256, 3) void k_edge(
    const float4* __restrict__ meta, const int* __restrict__ srcs,
    const int* __restrict__ dsts,
    const float* __restrict__ Wfc0, const float* __restrict__ Wfc1,
    const float* __restrict__ y, float* __restrict__ agg){
  __shared__ float s_wfc0[640];          // [k=10][n=64] f32, block-shared
  __shared__ float s_w [4][16*98];       // per-wave: [e=16][o=96(+2)]
  __shared__ float s_y [4][16*84];       // per-wave: y rows, stride 84
  __shared__ float s_m [4][16*20];       // per-wave: ea[0..3], es[4..13]

  const int t = threadIdx.x;
  const int w = t >> 6, l = t & 63;
  const int r = l & 15, part = l >> 4;

  for (int i = t; i < 640; i += 256) s_wfc0[i] = Wfc0[i];

  // B-fragments of Wfc1 (bf16) in registers: lane holds B[k=part*8+j][n=nt*16+r]
  short8 b0[6], b1[6];
  #pragma unroll
  for (int nt=0; nt<6; ++nt){
    #pragma unroll
    for (int j=0; j<8; ++j){
      b0[nt][j] = (short)f2bf(Wfc1[(     part*8+j)*96 + nt*16 + r]);
      b1[nt][j] = (short)f2bf(Wfc1[(32 + part*8+j)*96 + nt*16 + r]);
    }
  }
  __syncthreads();   // only block barrier: s_wfc0 ready

  // per-lane message-channel constants (3 channel passes, c = p*64 + l)
  int o_c[3], yo[3], eai[3];
  #pragma unroll
  for (int p=0; p<3; ++p){
    int c = p*64 + l;
    if (c < 32)      { o_c[p]=c;    yo[p]=c;        eai[p]=0; }
    else if (c < 48) { int u=c-32;  o_c[p]=80+u;    yo[p]=32+3*u; eai[p]=0; }
    else if (c < 144){ int idx=c-48;  int u=idx/3, fi=idx-u*3; o_c[p]=32+u; yo[p]=u;        eai[p]=1+fi; }
    else             { int idx=c-144; int u=idx/3, i =idx-u*3; o_c[p]=64+u; yo[p]=32+3*u+i; eai[p]=0; }
  }
  const bool dot0 = (l >= 32) && (l < 48);

  float* sw = s_w[w];
  float* sy = s_y[w];
  float* sm = s_m[w];

  const int gw = blockIdx.x*4 + w;
  const int nw = gridDim.x*4;
  const int m0 = (int)(((long long)gw     * N_MT) / nw);
  const int m1 = (int)(((long long)(gw+1) * N_MT) / nw);
  if (m0 >= m1) return;

  // ---- prologue: tile m0 meta/src/dst + y rows
  float4 mreg = meta[(size_t)m0*64 + l];
  int isrc = srcs[m0*16 + r];
  int idst = dsts[m0*16 + r];
  float4 yv0, yv1, yv2, yv3, yv4;
  {
    const float4* yp = (const float4*)(y + (size_t)isrc*80 + part*20);
    yv0 = yp[0]; yv1 = yp[1]; yv2 = yp[2]; yv3 = yp[3]; yv4 = yp[4];
  }

  float acc0 = 0.f, acc1 = 0.f, acc2 = 0.f;
  int dcur = -1;

  for (int m = m0; m < m1; ++m){
    // ---- stage current tile (regs -> LDS)
    *(float4*)(sm + (l>>2)*20 + (l&3)*4) = mreg;
    {
      float* syp = sy + r*84 + part*20;
      *(float4*)(syp     ) = yv0;
      *(float4*)(syp +  4) = yv1;
      *(float4*)(syp +  8) = yv2;
      *(float4*)(syp + 12) = yv3;
      *(float4*)(syp + 16) = yv4;
    }
    // ---- next-tile meta/src/dst prefetch (clamped, unconditional)
    const int mnx = (m+1 < m1) ? (m+1) : m;
    float4 mnext = meta[(size_t)mnx*64 + l];
    int isrc2 = srcs[mnx*16 + r];
    int idst2 = dsts[mnx*16 + r];
    wave_lds_fence();

    // ---- layer1: h[r][part*8+j] from s_m es
    const float* esr = sm + r*20 + 4;
    float hv0[8], hv1[8];
    #pragma unroll
    for (int j=0; j<8; ++j){ hv0[j]=0.f; hv1[j]=0.f; }
    #pragma unroll
    for (int k=0; k<10; ++k){
      float ev = esr[k];
      const float* wr = s_wfc0 + k*64 + part*8;
      #pragma unroll
      for (int j=0; j<8; ++j){ hv0[j] += ev*wr[j]; hv1[j] += ev*wr[32+j]; }
    }
    short8 a0, a1;
    #pragma unroll
    for (int j=0; j<8; ++j){
      float x0 = hv0[j]*0.31622776601683794f;   // /sqrt(10)
      float x1 = hv1[j]*0.31622776601683794f;
      a0[j] = (short)f2bf(x0/(1.f+__expf(-x0)));
      a1[j] = (short)f2bf(x1/(1.f+__expf(-x1)));
    }

    // ---- layer2 MFMA: w[e=part*4+rr][o=nt*16+r]
    #pragma unroll
    for (int nt=0; nt<6; ++nt){
      f32x4 acc = {0.f,0.f,0.f,0.f};
      acc = __builtin_amdgcn_mfma_f32_16x16x32_bf16(a0, b0[nt], acc, 0,0,0);
      acc = __builtin_amdgcn_mfma_f32_16x16x32_bf16(a1, b1[nt], acc, 0,0,0);
      #pragma unroll
      for (int rr=0; rr<4; ++rr)
        sw[(part*4+rr)*98 + nt*16 + r] = acc[rr]*0.125f;   // /sqrt(64)
    }

    // ---- next-tile y prefetch: latency overlaps the message loop.
    // Overwrites yv (current tile's copy already staged to LDS above).
    {
      const float4* ypn = (const float4*)(y + (size_t)isrc2*80 + part*20);
      yv0 = ypn[0]; yv1 = ypn[1]; yv2 = ypn[2]; yv3 = ypn[3]; yv4 = ypn[4];
    }
    wave_lds_fence();

    // ---- messages + carried segment-sum (3 channels per lane)
    for (int e=0; e<16; ++e){
      int de = __shfl(idst, e);
      if (de != dcur){
        if (dcur >= 0){
          unsafeAtomicAdd(&agg[(size_t)dcur*192 +       l], acc0);
          unsafeAtomicAdd(&agg[(size_t)dcur*192 +  64 + l], acc1);
          unsafeAtomicAdd(&agg[(size_t)dcur*192 + 128 + l], acc2);
        }
        acc0 = acc1 = acc2 = 0.f;
        dcur = de;
      }
      const float* sme = sm + e*20;
      const float* swe = sw + e*98;
      const float* sye = sy + e*84;
      float m0v;
      if (dot0){
        m0v = swe[o_c[0]] * (sye[yo[0]]*sme[1] + sye[yo[0]+1]*sme[2] + sye[yo[0]+2]*sme[3])
              * 0.5773502691896258f;   // /sqrt(3)
      } else {
        m0v = swe[o_c[0]] * sye[yo[0]] * sme[eai[0]];
      }
      acc0 += m0v;
      acc1 += swe[o_c[1]] * sye[yo[1]] * sme[eai[1]];
      acc2 += swe[o_c[2]] * sye[yo[2]] * sme[eai[2]];
    }
    wave_lds_fence();

    mreg = mnext; isrc = isrc2; idst = idst2;
  }
  if (dcur >= 0){
    unsafeAtomicAdd(&agg[(size_t)dcur*192 +       l], acc0);
    unsafeAtomicAdd(&agg[(size_t)dcur*192 +  64 + l], acc1);
    unsafeAtomicAdd(&agg[(size_t)dcur*192 + 128 + l], acc2);
  }
}

// ---------------- finish: z = agg @ W_l2, out = c_s*s + c_x*z ----------------
// LDS-staged, 16 nodes/block, 5 outputs/thread.
__global__ void k_finish(const float* __restrict__ ni, const float* __restrict__ na,
    const float* __restrict__ Wsc0, const float* __restrict__ Wsc1,
    const float* __restrict__ Wl20, const float* __restrict__ Wl21,
    const float* __restrict__ agg, float* __restrict__ out){
  __shared__ float sWsc0[1024];   // [32][32]
  __shared__ float sWsc1[256];    // [16][16]
  __shared__ float sWl20[1536];   // [48][32]
  __shared__ float sWl21[768];    // [48][16]
  __shared__ float sni[16*84];    // node rows, stride 84
  __shared__ float sag[16*196];   // agg rows, stride 196
  __shared__ float sna[16];
  const int t = threadIdx.x;
  const int nb = blockIdx.x*16;
  for (int i=t; i<1024; i+=256) sWsc0[i] = Wsc0[i];
  if (t < 256) sWsc1[t] = Wsc1[t];
  for (int i=t; i<1536; i+=256) sWl20[i] = Wl20[i];
  for (int i=t; i<768;  i+=256) sWl21[i] = Wl21[i];
  for (int i=t; i<320;  i+=256){
    int n = i/20, q = i - n*20;
    *(float4*)&sni[n*84 + q*4] = *(const float4*)(ni + (size_t)(nb+n)*80 + q*4);
  }
  for (int i=t; i<768;  i+=256){
    int n = i/48, q = i - n*48;
    *(float4*)&sag[n*196 + q*4] = *(const float4*)(agg + (size_t)(nb+n)*192 + q*4);
  }
  if (t < 16) sna[t] = na[nb + t];
  __syncthreads();

  const float c_s = 0.3826834323650898f;   // sin(pi/8)
  const float c_x = 0.9238795325112867f;   // cos(pi/8)
  const float zscale = 0.17677669529663687f * 0.14433756729740643f; // 1/sqrt(32)/sqrt(48)
  for (int i=t; i<1280; i+=256){
    int n = i/80, k = i - n*80;
    const float* row = sni + n*84;
    const float* ag  = sag + n*196;
    float a = sna[n];
    float s = 0.f, z = 0.f;
    if (k < 32){
      #pragma unroll
      for (int u=0; u<32; ++u) s += row[u]*sWsc0[u*32+k];
      s *= a * 0.17677669529663687f;
      #pragma unroll
      for (int u=0; u<48; ++u) z += ag[u]*sWl20[u*32+k];
    } else {
      int kk=k-32, v=kk/3, ii=kk-v*3;
      #pragma unroll
      for (int u=0; u<16; ++u) s += row[32+u*3+ii]*sWsc1[u*16+v];
      s *= a * 0.25f;
      #pragma unroll
      for (int u=0; u<48; ++u) z += ag[48+u*3+ii]*sWl21[u*16+v];
    }
    out[(size_t)nb*80 + i] = c_s*s + c_x*z*zscale;
  }
}

extern "C" void kernel_launch(void* const* d_in, const int* in_sizes, int n_in,
                              void* d_out, int out_size, void* d_ws, size_t ws_size,
                              hipStream_t stream){
  const float* node_input   = (const float*)d_in[0];
  const float* node_attr    = (const float*)d_in[1];
  const float* edge_attr    = (const float*)d_in[2];
  const float* edge_scalars = (const float*)d_in[3];
  const float* W_sc0 = (const float*)d_in[4];
  const float* W_sc1 = (const float*)d_in[5];
  const float* W_l1_0 = (const float*)d_in[6];
  const float* W_l1_1 = (const float*)d_in[7];
  const float* W_fc0 = (const float*)d_in[8];
  const float* W_fc1 = (const float*)d_in[9];
  const float* W_l2_0 = (const float*)d_in[10];
  const float* W_l2_1 = (const float*)d_in[11];
  const int* edge_index = (const int*)d_in[12];
  float* out = (float*)d_out;

  char* ws = (char*)d_ws;
  float*  y    = (float*)ws;                          //  6,400,000 B
  float*  agg  = (float*)(ws + 6400000);              // 15,360,000 B
  float4* meta = (float4*)(ws + 21760000);            // 40,960,000 B (16B-aligned)
  int* counts  = (int*)(ws + 62720000);               // 20000 ints
  int* ctr     = counts + 20000;                      // 1 int (+7 pad)
  int* cursor  = counts + 20008;                      // 20000 ints
  int* srcs    = cursor + 20000;                      // 640000 ints
  int* dsts    = srcs + N_EDGES;                      // 640000 ints

  hipMemsetAsync(agg, 0, (size_t)N_NODES*192*sizeof(float), stream);
  hipMemsetAsync(counts, 0, (size_t)20008*sizeof(int), stream);  // counts + ctr

  k_pre  <<<HIST_BLOCKS + YN_BLOCKS, 256, 0, stream>>>(edge_index, counts,
                                                       node_input, node_attr, W_l1_0, W_l1_1, y);
  k_alloc<<<(N_NODES+255)/256, 256, 0, stream>>>(counts, ctr, cursor);
  k_fill <<<(N_EDGES+255)/256, 256, 0, stream>>>(edge_index, edge_attr, edge_scalars,
                                                 cursor, meta, srcs, dsts);
  k_edge <<<768, 256, 0, stream>>>(meta, srcs, dsts, W_fc0, W_fc1, y, agg);
  k_finish<<<YN_BLOCKS, 256, 0, stream>>>(node_input, node_attr, W_sc0, W_sc1,
                                          W_l2_0, W_l2_1, agg, out);
}

// Round 8
// 364.049 us; speedup vs baseline: 1.5913x; 1.0905x over previous
//
#include <hip/hip_runtime.h>

#define N_NODES 20000
#define N_EDGES 640000
#define N_MT (N_EDGES/16)   // 40000 microtiles of 16 edges

typedef short short8 __attribute__((ext_vector_type(8)));
typedef float f32x4 __attribute__((ext_vector_type(4)));

// RNE float -> bf16 bits
__device__ __forceinline__ unsigned short f2bf(float x){
  unsigned int u = __builtin_bit_cast(unsigned int, x);
  u += 0x7fffu + ((u >> 16) & 1u);
  return (unsigned short)(u >> 16);
}

// wave-synchronous LDS phase boundary
__device__ __forceinline__ void wave_lds_fence(){
  __asm__ volatile("s_waitcnt lgkmcnt(0)" ::: "memory");
}

#define HIST_BLOCKS ((N_EDGES+255)/256)    // 2500
#define YN_BLOCKS   (N_NODES/16)           // 1250 (16 nodes per block)
#define AGGZ_BLOCKS 938                    // zero 3,840,000 floats, 16/thread

// ---- fused: edge-dst histogram + y = l1 linear + agg zeroing ----
__global__ void k_pre(const int* __restrict__ ei, int* __restrict__ counts,
                      const float* __restrict__ ni, const float* __restrict__ na,
                      const float* __restrict__ Wl10, const float* __restrict__ Wl11,
                      float* __restrict__ y, float4* __restrict__ aggz){
  if (blockIdx.x < HIST_BLOCKS){
    int e = blockIdx.x*256 + threadIdx.x;
    if (e < N_EDGES) atomicAdd(&counts[ei[N_EDGES + e]], 1);
    return;
  }
  if (blockIdx.x >= HIST_BLOCKS + YN_BLOCKS){
    // agg zeroing: 960000 float4s, 4 per thread
    int i = (blockIdx.x - HIST_BLOCKS - YN_BLOCKS)*256 + threadIdx.x;
    if (i < 240000){
      float4 z = {0.f,0.f,0.f,0.f};
      float4* p = aggz + (size_t)i*4;
      p[0]=z; p[1]=z; p[2]=z; p[3]=z;
    }
    return;
  }
  __shared__ float sW0[1024];     // Wl10 [32][32]
  __shared__ float sW1[256];      // Wl11 [16][16]
  __shared__ float sni[16*84];    // 16 node rows, stride 84
  __shared__ float sna[16];
  const int t = threadIdx.x;
  const int nb = (blockIdx.x - HIST_BLOCKS)*16;
  for (int i=t; i<1024; i+=256) sW0[i] = Wl10[i];
  if (t < 256) sW1[t] = Wl11[t];
  for (int i=t; i<320; i+=256){
    int n = i/20, q = i - n*20;
    *(float4*)&sni[n*84 + q*4] = *(const float4*)(ni + (size_t)(nb+n)*80 + q*4);
  }
  if (t < 16) sna[t] = na[nb + t];
  __syncthreads();
  for (int i=t; i<1280; i+=256){
    int n = i/80, k = i - n*80;
    const float* row = sni + n*84;
    float a = sna[n];
    float acc = 0.f;
    if (k < 32){
      #pragma unroll
      for (int u=0; u<32; ++u) acc += row[u]*sW0[u*32+k];
      y[(size_t)nb*80 + i] = acc * a * 0.17677669529663687f;  // 1/sqrt(32)
    } else {
      int kk = k-32, v = kk/3, ii = kk - v*3;
      #pragma unroll
      for (int u=0; u<16; ++u) acc += row[32+u*3+ii]*sW1[u*16+v];
      y[(size_t)nb*80 + i] = acc * a * 0.25f;                  // 1/sqrt(16)
    }
  }
}

__global__ void k_alloc(const int* __restrict__ counts, int* __restrict__ ctr,
                        int* __restrict__ cursor){
  int n = blockIdx.x*256 + threadIdx.x;
  if (n < N_NODES) cursor[n] = atomicAdd(ctr, counts[n]);
}

// One 64B record per edge at its sorted position:
// f[16] = {ea0..ea3, es0..es9, src, dst}
__global__ void k_fill(const int* __restrict__ ei, const float* __restrict__ ea,
                       const float* __restrict__ es, int* __restrict__ cursor,
                       float4* __restrict__ meta){
  int e = blockIdx.x*256 + threadIdx.x;
  if (e >= N_EDGES) return;
  int s = ei[e], d = ei[N_EDGES + e];
  int pos = atomicAdd(&cursor[d], 1);
  const float* eap = ea + (size_t)e*4;
  const float* esp = es + (size_t)e*10;
  float4 v0, v1, v2, v3;
  v0.x = eap[0]; v0.y = eap[1]; v0.z = eap[2]; v0.w = eap[3];
  v1.x = esp[0]; v1.y = esp[1]; v1.z = esp[2]; v1.w = esp[3];
  v2.x = esp[4]; v2.y = esp[5]; v2.z = esp[6]; v2.w = esp[7];
  v3.x = esp[8]; v3.y = esp[9];
  v3.z = __int_as_float(s); v3.w = __int_as_float(d);
  float4* mp = meta + (size_t)pos*4;
  mp[0] = v0; mp[1] = v1; mp[2] = v2; mp[3] = v3;
}

// ---------------- fused edge MLP + messages + segment-sum ----------------
// Round-6 proven flow: y rows global->reg->LDS at loop top (short live
// ranges); only next-tile meta (4 VGPRs) crosses the compute phases.
// src/dst extracted from meta via shfl (lane 4r+3 holds {es8,es9,src,dst}).
__global__ __launch_bounds__(256, 3) void k_edge(
    const float4* __restrict__ meta,
    const float* __restrict__ Wfc0, const float* __restrict__ Wfc1,
    const float* __restrict__ y, float* __restrict__ agg){
  __shared__ float s_wfc0[640];          // [k=10][n=64] f32, block-shared
  __shared__ float s_w [4][16*98];       // per-wave: [e=16][o=96(+2)]
  __shared__ float s_y [4][16*84];       // per-wave: y rows, stride 84
  __shared__ float s_m [4][16*20];       // per-wave: ea[0..3], es[4..13], src/dst[14..15]

  const int t = threadIdx.x;
  const int w = t >> 6, l = t & 63;
  const int r = l & 15, part = l >> 4;

  for (int i = t; i < 640; i += 256) s_wfc0[i] = Wfc0[i];

  // B-fragments of Wfc1 (bf16) in registers: lane holds B[k=part*8+j][n=nt*16+r]
  short8 b0[6], b1[6];
  #pragma unroll
  for (int nt=0; nt<6; ++nt){
    #pragma unroll
    for (int j=0; j<8; ++j){
      b0[nt][j] = (short)f2bf(Wfc1[(     part*8+j)*96 + nt*16 + r]);
      b1[nt][j] = (short)f2bf(Wfc1[(32 + part*8+j)*96 + nt*16 + r]);
    }
  }
  __syncthreads();   // only block barrier: s_wfc0 ready

  // per-lane message-channel constants (3 channel passes, c = p*64 + l)
  int o_c[3], yo[3], eai[3];
  #pragma unroll
  for (int p=0; p<3; ++p){
    int c = p*64 + l;
    if (c < 32)      { o_c[p]=c;    yo[p]=c;        eai[p]=0; }
    else if (c < 48) { int u=c-32;  o_c[p]=80+u;    yo[p]=32+3*u; eai[p]=0; }
    else if (c < 144){ int idx=c-48;  int u=idx/3, fi=idx-u*3; o_c[p]=32+u; yo[p]=u;        eai[p]=1+fi; }
    else             { int idx=c-144; int u=idx/3, i =idx-u*3; o_c[p]=64+u; yo[p]=32+3*u+i; eai[p]=0; }
  }
  const bool dot0 = (l >= 32) && (l < 48);

  float* sw = s_w[w];
  float* sy = s_y[w];
  float* sm = s_m[w];

  const int gw = blockIdx.x*4 + w;
  const int nw = gridDim.x*4;
  const int m0 = (int)(((long long)gw     * N_MT) / nw);
  const int m1 = (int)(((long long)(gw+1) * N_MT) / nw);
  if (m0 >= m1) return;

  // ---- prologue: tile m0 meta
  float4 mreg = meta[(size_t)m0*64 + l];

  float acc0 = 0.f, acc1 = 0.f, acc2 = 0.f;
  int dcur = -1;

  for (int m = m0; m < m1; ++m){
    // ---- next-tile meta prefetch (clamped; only 4 VGPRs cross phases)
    const int mnx = (m+1 < m1) ? (m+1) : m;
    float4 mnext = meta[(size_t)mnx*64 + l];

    // ---- extract src/dst for this tile from mreg
    const int isrc = __float_as_int(__shfl(mreg.z, 4*r + 3));
    const int idst = __float_as_int(__shfl(mreg.w, 4*r + 3));

    // ---- current-tile y gather (global->reg->LDS, short live range)
    float4 yv0, yv1, yv2, yv3, yv4;
    {
      const float4* yp = (const float4*)(y + (size_t)isrc*80 + part*20);
      yv0 = yp[0]; yv1 = yp[1]; yv2 = yp[2]; yv3 = yp[3]; yv4 = yp[4];
    }
    // ---- stage LDS
    *(float4*)(sm + (l>>2)*20 + (l&3)*4) = mreg;
    {
      float* syp = sy + r*84 + part*20;
      *(float4*)(syp     ) = yv0;
      *(float4*)(syp +  4) = yv1;
      *(float4*)(syp +  8) = yv2;
      *(float4*)(syp + 12) = yv3;
      *(float4*)(syp + 16) = yv4;
    }
    wave_lds_fence();

    // ---- layer1: h[r][part*8+j] from s_m es
    const float* esr = sm + r*20 + 4;
    float hv0[8], hv1[8];
    #pragma unroll
    for (int j=0; j<8; ++j){ hv0[j]=0.f; hv1[j]=0.f; }
    #pragma unroll
    for (int k=0; k<10; ++k){
      float ev = esr[k];
      const float* wr = s_wfc0 + k*64 + part*8;
      #pragma unroll
      for (int j=0; j<8; ++j){ hv0[j] += ev*wr[j]; hv1[j] += ev*wr[32+j]; }
    }
    short8 a0, a1;
    #pragma unroll
    for (int j=0; j<8; ++j){
      float x0 = hv0[j]*0.31622776601683794f;   // /sqrt(10)
      float x1 = hv1[j]*0.31622776601683794f;
      a0[j] = (short)f2bf(x0/(1.f+__expf(-x0)));
      a1[j] = (short)f2bf(x1/(1.f+__expf(-x1)));
    }

    // ---- layer2 MFMA: w[e=part*4+rr][o=nt*16+r]
    #pragma unroll
    for (int nt=0; nt<6; ++nt){
      f32x4 acc = {0.f,0.f,0.f,0.f};
      acc = __builtin_amdgcn_mfma_f32_16x16x32_bf16(a0, b0[nt], acc, 0,0,0);
      acc = __builtin_amdgcn_mfma_f32_16x16x32_bf16(a1, b1[nt], acc, 0,0,0);
      #pragma unroll
      for (int rr=0; rr<4; ++rr)
        sw[(part*4+rr)*98 + nt*16 + r] = acc[rr]*0.125f;   // /sqrt(64)
    }
    wave_lds_fence();

    // ---- messages + carried segment-sum (3 channels per lane)
    for (int e=0; e<16; ++e){
      int de = __shfl(idst, e);
      if (de != dcur){
        if (dcur >= 0){
          unsafeAtomicAdd(&agg[(size_t)dcur*192 +       l], acc0);
          unsafeAtomicAdd(&agg[(size_t)dcur*192 +  64 + l], acc1);
          unsafeAtomicAdd(&agg[(size_t)dcur*192 + 128 + l], acc2);
        }
        acc0 = acc1 = acc2 = 0.f;
        dcur = de;
      }
      const float* sme = sm + e*20;
      const float* swe = sw + e*98;
      const float* sye = sy + e*84;
      float m0v;
      if (dot0){
        m0v = swe[o_c[0]] * (sye[yo[0]]*sme[1] + sye[yo[0]+1]*sme[2] + sye[yo[0]+2]*sme[3])
              * 0.5773502691896258f;   // /sqrt(3)
      } else {
        m0v = swe[o_c[0]] * sye[yo[0]] * sme[eai[0]];
      }
      acc0 += m0v;
      acc1 += swe[o_c[1]] * sye[yo[1]] * sme[eai[1]];
      acc2 += swe[o_c[2]] * sye[yo[2]] * sme[eai[2]];
    }
    wave_lds_fence();

    mreg = mnext;
  }
  if (dcur >= 0){
    unsafeAtomicAdd(&agg[(size_t)dcur*192 +       l], acc0);
    unsafeAtomicAdd(&agg[(size_t)dcur*192 +  64 + l], acc1);
    unsafeAtomicAdd(&agg[(size_t)dcur*192 + 128 + l], acc2);
  }
}

// ---------------- finish: z = agg @ W_l2, out = c_s*s + c_x*z ----------------
// LDS-staged, 16 nodes/block, 5 outputs/thread.
__global__ void k_finish(const float* __restrict__ ni, const float* __restrict__ na,
    const float* __restrict__ Wsc0, const float* __restrict__ Wsc1,
    const float* __restrict__ Wl20, const float* __restrict__ Wl21,
    const float* __restrict__ agg, float* __restrict__ out){
  __shared__ float sWsc0[1024];   // [32][32]
  __shared__ float sWsc1[256];    // [16][16]
  __shared__ float sWl20[1536];   // [48][32]
  __shared__ float sWl21[768];    // [48][16]
  __shared__ float sni[16*84];    // node rows, stride 84
  __shared__ float sag[16*196];   // agg rows, stride 196
  __shared__ float sna[16];
  const int t = threadIdx.x;
  const int nb = blockIdx.x*16;
  for (int i=t; i<1024; i+=256) sWsc0[i] = Wsc0[i];
  if (t < 256) sWsc1[t] = Wsc1[t];
  for (int i=t; i<1536; i+=256) sWl20[i] = Wl20[i];
  for (int i=t; i<768;  i+=256) sWl21[i] = Wl21[i];
  for (int i=t; i<320;  i+=256){
    int n = i/20, q = i - n*20;
    *(float4*)&sni[n*84 + q*4] = *(const float4*)(ni + (size_t)(nb+n)*80 + q*4);
  }
  for (int i=t; i<768;  i+=256){
    int n = i/48, q = i - n*48;
    *(float4*)&sag[n*196 + q*4] = *(const float4*)(agg + (size_t)(nb+n)*192 + q*4);
  }
  if (t < 16) sna[t] = na[nb + t];
  __syncthreads();

  const float c_s = 0.3826834323650898f;   // sin(pi/8)
  const float c_x = 0.9238795325112867f;   // cos(pi/8)
  const float zscale = 0.17677669529663687f * 0.14433756729740643f; // 1/sqrt(32)/sqrt(48)
  for (int i=t; i<1280; i+=256){
    int n = i/80, k = i - n*80;
    const float* row = sni + n*84;
    const float* ag  = sag + n*196;
    float a = sna[n];
    float s = 0.f, z = 0.f;
    if (k < 32){
      #pragma unroll
      for (int u=0; u<32; ++u) s += row[u]*sWsc0[u*32+k];
      s *= a * 0.17677669529663687f;
      #pragma unroll
      for (int u=0; u<48; ++u) z += ag[u]*sWl20[u*32+k];
    } else {
      int kk=k-32, v=kk/3, ii=kk-v*3;
      #pragma unroll
      for (int u=0; u<16; ++u) s += row[32+u*3+ii]*sWsc1[u*16+v];
      s *= a * 0.25f;
      #pragma unroll
      for (int u=0; u<48; ++u) z += ag[48+u*3+ii]*sWl21[u*16+v];
    }
    out[(size_t)nb*80 + i] = c_s*s + c_x*z*zscale;
  }
}

extern "C" void kernel_launch(void* const* d_in, const int* in_sizes, int n_in,
                              void* d_out, int out_size, void* d_ws, size_t ws_size,
                              hipStream_t stream){
  const float* node_input   = (const float*)d_in[0];
  const float* node_attr    = (const float*)d_in[1];
  const float* edge_attr    = (const float*)d_in[2];
  const float* edge_scalars = (const float*)d_in[3];
  const float* W_sc0 = (const float*)d_in[4];
  const float* W_sc1 = (const float*)d_in[5];
  const float* W_l1_0 = (const float*)d_in[6];
  const float* W_l1_1 = (const float*)d_in[7];
  const float* W_fc0 = (const float*)d_in[8];
  const float* W_fc1 = (const float*)d_in[9];
  const float* W_l2_0 = (const float*)d_in[10];
  const float* W_l2_1 = (const float*)d_in[11];
  const int* edge_index = (const int*)d_in[12];
  float* out = (float*)d_out;

  char* ws = (char*)d_ws;
  float*  y      = (float*)ws;                        //  6,400,000 B
  float*  agg    = (float*)(ws + 6400000);            // 15,360,000 B
  int*    counts = (int*)(ws + 21760000);             // 80,000 B
  int*    ctr    = (int*)(ws + 21840000);             // 64 B
  int*    cursor = (int*)(ws + 21840064);             // 80,000 B
  float4* meta   = (float4*)(ws + 22400000);          // 40,960,000 B (64-aligned)

  // zero counts + ctr only (agg zeroed inside k_pre)
  hipMemsetAsync(counts, 0, 80064, stream);

  k_pre  <<<HIST_BLOCKS + YN_BLOCKS + AGGZ_BLOCKS, 256, 0, stream>>>(
            edge_index, counts, node_input, node_attr, W_l1_0, W_l1_1,
            y, (float4*)agg);
  k_alloc<<<(N_NODES+255)/256, 256, 0, stream>>>(counts, ctr, cursor);
  k_fill <<<(N_EDGES+255)/256, 256, 0, stream>>>(edge_index, edge_attr, edge_scalars,
                                                 cursor, meta);
  k_edge <<<768, 256, 0, stream>>>(meta, W_fc0, W_fc1, y, agg);
  k_finish<<<YN_BLOCKS, 256, 0, stream>>>(node_input, node_attr, W_sc0, W_sc1,
                                          W_l2_0, W_l2_1, agg, out);
}

// Round 9
// 354.456 us; speedup vs baseline: 1.6343x; 1.0271x over previous
//
#include <hip/hip_runtime.h>

#define N_NODES 20000
#define N_EDGES 640000
#define N_MT (N_EDGES/16)   // 40000 microtiles of 16 edges

typedef short short8 __attribute__((ext_vector_type(8)));
typedef float f32x4 __attribute__((ext_vector_type(4)));

// RNE float -> bf16 bits
__device__ __forceinline__ unsigned short f2bf(float x){
  unsigned int u = __builtin_bit_cast(unsigned int, x);
  u += 0x7fffu + ((u >> 16) & 1u);
  return (unsigned short)(u >> 16);
}
__device__ __forceinline__ float bf2f(unsigned short u){
  unsigned int v = ((unsigned int)u) << 16;
  return __builtin_bit_cast(float, v);
}

// wave-synchronous LDS phase boundary
__device__ __forceinline__ void wave_lds_fence(){
  __asm__ volatile("s_waitcnt lgkmcnt(0)" ::: "memory");
}

#define HIST_BLOCKS ((N_EDGES+255)/256)    // 2500
#define YN_BLOCKS   (N_NODES/16)           // 1250 (16 nodes per block)
#define AGGZ_BLOCKS 938                    // zero 3,840,000 floats, 16/thread

// ---- fused: edge-dst histogram + y = l1 linear (bf16 out) + agg zeroing ----
__global__ void k_pre(const int* __restrict__ ei, int* __restrict__ counts,
                      const float* __restrict__ ni, const float* __restrict__ na,
                      const float* __restrict__ Wl10, const float* __restrict__ Wl11,
                      unsigned short* __restrict__ y, float4* __restrict__ aggz){
  if (blockIdx.x < HIST_BLOCKS){
    int e = blockIdx.x*256 + threadIdx.x;
    if (e < N_EDGES) atomicAdd(&counts[ei[N_EDGES + e]], 1);
    return;
  }
  if (blockIdx.x >= HIST_BLOCKS + YN_BLOCKS){
    int i = (blockIdx.x - HIST_BLOCKS - YN_BLOCKS)*256 + threadIdx.x;
    if (i < 240000){
      float4 z = {0.f,0.f,0.f,0.f};
      float4* p = aggz + (size_t)i*4;
      p[0]=z; p[1]=z; p[2]=z; p[3]=z;
    }
    return;
  }
  __shared__ float sW0[1024];     // Wl10 [32][32]
  __shared__ float sW1[256];      // Wl11 [16][16]
  __shared__ float sni[16*84];    // 16 node rows, stride 84
  __shared__ float sna[16];
  const int t = threadIdx.x;
  const int nb = (blockIdx.x - HIST_BLOCKS)*16;
  for (int i=t; i<1024; i+=256) sW0[i] = Wl10[i];
  if (t < 256) sW1[t] = Wl11[t];
  for (int i=t; i<320; i+=256){
    int n = i/20, q = i - n*20;
    *(float4*)&sni[n*84 + q*4] = *(const float4*)(ni + (size_t)(nb+n)*80 + q*4);
  }
  if (t < 16) sna[t] = na[nb + t];
  __syncthreads();
  for (int i=t; i<1280; i+=256){
    int n = i/80, k = i - n*80;
    const float* row = sni + n*84;
    float a = sna[n];
    float acc = 0.f;
    if (k < 32){
      #pragma unroll
      for (int u=0; u<32; ++u) acc += row[u]*sW0[u*32+k];
      y[(size_t)nb*80 + i] = f2bf(acc * a * 0.17677669529663687f);  // 1/sqrt(32)
    } else {
      int kk = k-32, v = kk/3, ii = kk - v*3;
      #pragma unroll
      for (int u=0; u<16; ++u) acc += row[32+u*3+ii]*sW1[u*16+v];
      y[(size_t)nb*80 + i] = f2bf(acc * a * 0.25f);                  // 1/sqrt(16)
    }
  }
}

__global__ void k_alloc(const int* __restrict__ counts, int* __restrict__ ctr,
                        int* __restrict__ cursor){
  int n = blockIdx.x*256 + threadIdx.x;
  if (n < N_NODES) cursor[n] = atomicAdd(ctr, counts[n]);
}

// One 64B record per edge at its sorted position:
// f[16] = {ea0..ea3, es0..es9, src, dst}
__global__ void k_fill(const int* __restrict__ ei, const float* __restrict__ ea,
                       const float* __restrict__ es, int* __restrict__ cursor,
                       float4* __restrict__ meta){
  int e = blockIdx.x*256 + threadIdx.x;
  if (e >= N_EDGES) return;
  int s = ei[e], d = ei[N_EDGES + e];
  int pos = atomicAdd(&cursor[d], 1);
  const float* eap = ea + (size_t)e*4;
  const float* esp = es + (size_t)e*10;
  float4 v0, v1, v2, v3;
  v0.x = eap[0]; v0.y = eap[1]; v0.z = eap[2]; v0.w = eap[3];
  v1.x = esp[0]; v1.y = esp[1]; v1.z = esp[2]; v1.w = esp[3];
  v2.x = esp[4]; v2.y = esp[5]; v2.z = esp[6]; v2.w = esp[7];
  v3.x = esp[8]; v3.y = esp[9];
  v3.z = __int_as_float(s); v3.w = __int_as_float(d);
  float4* mp = meta + (size_t)pos*4;
  mp[0] = v0; mp[1] = v1; mp[2] = v2; mp[3] = v3;
}

// ---------------- fused edge MLP + messages + segment-sum ----------------
// Round-8 flow, bf16 y + bf16 w in LDS => 31.5 KB/block => 5 blocks/CU.
__global__ __launch_bounds__(256, 5) void k_edge(
    const float4* __restrict__ meta,
    const float* __restrict__ Wfc0, const float* __restrict__ Wfc1,
    const unsigned short* __restrict__ yb, float* __restrict__ agg){
  __shared__ float s_wfc0[640];                    // [k=10][n=64] f32
  __shared__ unsigned short s_w[4][16*98];         // per-wave: [e=16][o=96(+2)] bf16
  __shared__ unsigned short s_y[4][16*88];         // per-wave: y rows bf16, stride 88 (176B, 16B-aligned)
  __shared__ float s_m[4][16*20];                  // per-wave: ea[0..3], es[4..13], src/dst[14..15]

  const int t = threadIdx.x;
  const int w = t >> 6, l = t & 63;
  const int r = l & 15, part = l >> 4;

  for (int i = t; i < 640; i += 256) s_wfc0[i] = Wfc0[i];

  // B-fragments of Wfc1 (bf16) in registers: lane holds B[k=part*8+j][n=nt*16+r]
  short8 b0[6], b1[6];
  #pragma unroll
  for (int nt=0; nt<6; ++nt){
    #pragma unroll
    for (int j=0; j<8; ++j){
      b0[nt][j] = (short)f2bf(Wfc1[(     part*8+j)*96 + nt*16 + r]);
      b1[nt][j] = (short)f2bf(Wfc1[(32 + part*8+j)*96 + nt*16 + r]);
    }
  }
  __syncthreads();   // only block barrier: s_wfc0 ready

  // per-lane message-channel constants (3 channel passes, c = p*64 + l)
  int o_c[3], yo[3], eai[3];
  #pragma unroll
  for (int p=0; p<3; ++p){
    int c = p*64 + l;
    if (c < 32)      { o_c[p]=c;    yo[p]=c;        eai[p]=0; }
    else if (c < 48) { int u=c-32;  o_c[p]=80+u;    yo[p]=32+3*u; eai[p]=0; }
    else if (c < 144){ int idx=c-48;  int u=idx/3, fi=idx-u*3; o_c[p]=32+u; yo[p]=u;        eai[p]=1+fi; }
    else             { int idx=c-144; int u=idx/3, i =idx-u*3; o_c[p]=64+u; yo[p]=32+3*u+i; eai[p]=0; }
  }
  const bool dot0 = (l >= 32) && (l < 48);

  unsigned short* sw = s_w[w];
  unsigned short* sy = s_y[w];
  float* sm = s_m[w];

  // y-row chunk assignment (16B chunks of the 160B bf16 row):
  // part0: ushort offs 0,8,16 ; part1: 24,32 ; part2: 40,48,56 ; part3: 64,72
  const int o0 = (part==0) ? 0 : (part==1) ? 24 : (part==2) ? 40 : 64;
  const bool has3 = (part & 1) == 0;

  const int gw = blockIdx.x*4 + w;
  const int nw = gridDim.x*4;
  const int m0 = (int)(((long long)gw     * N_MT) / nw);
  const int m1 = (int)(((long long)(gw+1) * N_MT) / nw);
  if (m0 >= m1) return;

  // ---- prologue: tile m0 meta
  float4 mreg = meta[(size_t)m0*64 + l];

  float acc0 = 0.f, acc1 = 0.f, acc2 = 0.f;
  int dcur = -1;

  for (int m = m0; m < m1; ++m){
    // ---- next-tile meta prefetch (clamped; only 4 VGPRs cross phases)
    const int mnx = (m+1 < m1) ? (m+1) : m;
    float4 mnext = meta[(size_t)mnx*64 + l];

    // ---- extract src/dst for this tile from mreg
    const int isrc = __float_as_int(__shfl(mreg.z, 4*r + 3));
    const int idst = __float_as_int(__shfl(mreg.w, 4*r + 3));

    // ---- current-tile y gather, bf16 (global->reg->LDS, short live range)
    {
      const unsigned short* yrow = yb + (size_t)isrc*80;
      uint4 va = *(const uint4*)(yrow + o0);
      uint4 vb = *(const uint4*)(yrow + o0 + 8);
      uint4 vc;
      if (has3) vc = *(const uint4*)(yrow + o0 + 16);
      unsigned short* syr = sy + r*88;
      *(uint4*)(syr + o0)      = va;
      *(uint4*)(syr + o0 + 8)  = vb;
      if (has3) *(uint4*)(syr + o0 + 16) = vc;
    }
    *(float4*)(sm + (l>>2)*20 + (l&3)*4) = mreg;
    wave_lds_fence();

    // ---- layer1: h[r][part*8+j] from s_m es
    const float* esr = sm + r*20 + 4;
    float hv0[8], hv1[8];
    #pragma unroll
    for (int j=0; j<8; ++j){ hv0[j]=0.f; hv1[j]=0.f; }
    #pragma unroll
    for (int k=0; k<10; ++k){
      float ev = esr[k];
      const float* wr = s_wfc0 + k*64 + part*8;
      #pragma unroll
      for (int j=0; j<8; ++j){ hv0[j] += ev*wr[j]; hv1[j] += ev*wr[32+j]; }
    }
    short8 a0, a1;
    #pragma unroll
    for (int j=0; j<8; ++j){
      float x0 = hv0[j]*0.31622776601683794f;   // /sqrt(10)
      float x1 = hv1[j]*0.31622776601683794f;
      a0[j] = (short)f2bf(x0/(1.f+__expf(-x0)));
      a1[j] = (short)f2bf(x1/(1.f+__expf(-x1)));
    }

    // ---- layer2 MFMA: w[e=part*4+rr][o=nt*16+r] -> bf16 LDS
    #pragma unroll
    for (int nt=0; nt<6; ++nt){
      f32x4 acc = {0.f,0.f,0.f,0.f};
      acc = __builtin_amdgcn_mfma_f32_16x16x32_bf16(a0, b0[nt], acc, 0,0,0);
      acc = __builtin_amdgcn_mfma_f32_16x16x32_bf16(a1, b1[nt], acc, 0,0,0);
      #pragma unroll
      for (int rr=0; rr<4; ++rr)
        sw[(part*4+rr)*98 + nt*16 + r] = f2bf(acc[rr]*0.125f);   // /sqrt(64)
    }
    wave_lds_fence();

    // ---- messages + carried segment-sum (3 channels per lane)
    for (int e=0; e<16; ++e){
      int de = __shfl(idst, e);
      if (de != dcur){
        if (dcur >= 0){
          unsafeAtomicAdd(&agg[(size_t)dcur*192 +       l], acc0);
          unsafeAtomicAdd(&agg[(size_t)dcur*192 +  64 + l], acc1);
          unsafeAtomicAdd(&agg[(size_t)dcur*192 + 128 + l], acc2);
        }
        acc0 = acc1 = acc2 = 0.f;
        dcur = de;
      }
      const float* sme = sm + e*20;
      const unsigned short* swe = sw + e*98;
      const unsigned short* sye = sy + e*88;
      float m0v;
      if (dot0){
        m0v = bf2f(swe[o_c[0]]) *
              (bf2f(sye[yo[0]])*sme[1] + bf2f(sye[yo[0]+1])*sme[2] + bf2f(sye[yo[0]+2])*sme[3])
              * 0.5773502691896258f;   // /sqrt(3)
      } else {
        m0v = bf2f(swe[o_c[0]]) * bf2f(sye[yo[0]]) * sme[eai[0]];
      }
      acc0 += m0v;
      acc1 += bf2f(swe[o_c[1]]) * bf2f(sye[yo[1]]) * sme[eai[1]];
      acc2 += bf2f(swe[o_c[2]]) * bf2f(sye[yo[2]]) * sme[eai[2]];
    }
    wave_lds_fence();

    mreg = mnext;
  }
  if (dcur >= 0){
    unsafeAtomicAdd(&agg[(size_t)dcur*192 +       l], acc0);
    unsafeAtomicAdd(&agg[(size_t)dcur*192 +  64 + l], acc1);
    unsafeAtomicAdd(&agg[(size_t)dcur*192 + 128 + l], acc2);
  }
}

// ---------------- finish: z = agg @ W_l2, out = c_s*s + c_x*z ----------------
__global__ void k_finish(const float* __restrict__ ni, const float* __restrict__ na,
    const float* __restrict__ Wsc0, const float* __restrict__ Wsc1,
    const float* __restrict__ Wl20, const float* __restrict__ Wl21,
    const float* __restrict__ agg, float* __restrict__ out){
  __shared__ float sWsc0[1024];   // [32][32]
  __shared__ float sWsc1[256];    // [16][16]
  __shared__ float sWl20[1536];   // [48][32]
  __shared__ float sWl21[768];    // [48][16]
  __shared__ float sni[16*84];    // node rows, stride 84
  __shared__ float sag[16*196];   // agg rows, stride 196
  __shared__ float sna[16];
  const int t = threadIdx.x;
  const int nb = blockIdx.x*16;
  for (int i=t; i<1024; i+=256) sWsc0[i] = Wsc0[i];
  if (t < 256) sWsc1[t] = Wsc1[t];
  for (int i=t; i<1536; i+=256) sWl20[i] = Wl20[i];
  for (int i=t; i<768;  i+=256) sWl21[i] = Wl21[i];
  for (int i=t; i<320;  i+=256){
    int n = i/20, q = i - n*20;
    *(float4*)&sni[n*84 + q*4] = *(const float4*)(ni + (size_t)(nb+n)*80 + q*4);
  }
  for (int i=t; i<768;  i+=256){
    int n = i/48, q = i - n*48;
    *(float4*)&sag[n*196 + q*4] = *(const float4*)(agg + (size_t)(nb+n)*192 + q*4);
  }
  if (t < 16) sna[t] = na[nb + t];
  __syncthreads();

  const float c_s = 0.3826834323650898f;   // sin(pi/8)
  const float c_x = 0.9238795325112867f;   // cos(pi/8)
  const float zscale = 0.17677669529663687f * 0.14433756729740643f; // 1/sqrt(32)/sqrt(48)
  for (int i=t; i<1280; i+=256){
    int n = i/80, k = i - n*80;
    const float* row = sni + n*84;
    const float* ag  = sag + n*196;
    float a = sna[n];
    float s = 0.f, z = 0.f;
    if (k < 32){
      #pragma unroll
      for (int u=0; u<32; ++u) s += row[u]*sWsc0[u*32+k];
      s *= a * 0.17677669529663687f;
      #pragma unroll
      for (int u=0; u<48; ++u) z += ag[u]*sWl20[u*32+k];
    } else {
      int kk=k-32, v=kk/3, ii=kk-v*3;
      #pragma unroll
      for (int u=0; u<16; ++u) s += row[32+u*3+ii]*sWsc1[u*16+v];
      s *= a * 0.25f;
      #pragma unroll
      for (int u=0; u<48; ++u) z += ag[48+u*3+ii]*sWl21[u*16+v];
    }
    out[(size_t)nb*80 + i] = c_s*s + c_x*z*zscale;
  }
}

extern "C" void kernel_launch(void* const* d_in, const int* in_sizes, int n_in,
                              void* d_out, int out_size, void* d_ws, size_t ws_size,
                              hipStream_t stream){
  const float* node_input   = (const float*)d_in[0];
  const float* node_attr    = (const float*)d_in[1];
  const float* edge_attr    = (const float*)d_in[2];
  const float* edge_scalars = (const float*)d_in[3];
  const float* W_sc0 = (const float*)d_in[4];
  const float* W_sc1 = (const float*)d_in[5];
  const float* W_l1_0 = (const float*)d_in[6];
  const float* W_l1_1 = (const float*)d_in[7];
  const float* W_fc0 = (const float*)d_in[8];
  const float* W_fc1 = (const float*)d_in[9];
  const float* W_l2_0 = (const float*)d_in[10];
  const float* W_l2_1 = (const float*)d_in[11];
  const int* edge_index = (const int*)d_in[12];
  float* out = (float*)d_out;

  char* ws = (char*)d_ws;
  unsigned short* y = (unsigned short*)ws;            //  3,200,000 B (bf16)
  float*  agg    = (float*)(ws + 3200000);            // 15,360,000 B
  int*    counts = (int*)(ws + 18560000);             // 80,000 B
  int*    ctr    = (int*)(ws + 18640000);             // 64 B
  int*    cursor = (int*)(ws + 18640064);             // 80,000 B
  float4* meta   = (float4*)(ws + 18720064 + 1984);   // 40,960,000 B (64-aligned @18722048)

  // zero counts + ctr only (agg zeroed inside k_pre)
  hipMemsetAsync(counts, 0, 80064, stream);

  k_pre  <<<HIST_BLOCKS + YN_BLOCKS + AGGZ_BLOCKS, 256, 0, stream>>>(
            edge_index, counts, node_input, node_attr, W_l1_0, W_l1_1,
            y, (float4*)agg);
  k_alloc<<<(N_NODES+255)/256, 256, 0, stream>>>(counts, ctr, cursor);
  k_fill <<<(N_EDGES+255)/256, 256, 0, stream>>>(edge_index, edge_attr, edge_scalars,
                                                 cursor, meta);
  k_edge <<<1280, 256, 0, stream>>>(meta, W_fc0, W_fc1, y, agg);
  k_finish<<<YN_BLOCKS, 256, 0, stream>>>(node_input, node_attr, W_sc0, W_sc1,
                                          W_l2_0, W_l2_1, agg, out);
}